// Round 3
// baseline (98.238 us; speedup 1.0000x reference)
//
#include <hip/hip_runtime.h>

#define NROWS 2048
#define MLEN  3000
#define LPAD  4096
#define PAD0  548
#define NLVL  8
#define NT    256

union F4 { float4 v; float f[4]; };

// Light barrier: LDS-visibility only (s_waitcnt lgkmcnt(0) + s_barrier), the
// composable_kernel block_sync_lds() idiom. Unlike __syncthreads() it does NOT
// drain vmcnt, so the details->global write-through stays in flight across
// analysis level boundaries.
__device__ inline void lds_barrier() {
    asm volatile("s_waitcnt lgkmcnt(0)\n\ts_barrier" ::: "memory");
}

// LDS 18.5KB (SA 8K + SB 8.5K + CS 2K) -> 8 blocks/CU, 32 waves.
// Coalesced two-half staging through SB; split-layout ([ev|od]) b128 LDS compute.
// Detail mirrors so synthesis lvl>=1 never reads global:
//   lvl>=3 -> CS[coff-3584], lvl2 -> SA[512..1024), lvl1 -> SB[1088..2112)
// R6: s_setprio(1) around FMA bursts (T5).
// R7: filters in SGPRs — taps s_load'ed from global scaling/scaling_rec at
// wave-uniform indices; wavelet sign (-1)^k folded into fmaf neg modifier,
// 7-k reversal folded into indexing. Frees ~16 VGPRs/thread under the
// __launch_bounds__(256,8) 64-VGPR cap; deletes fwav/fsca LDS arrays + init.
__global__ __launch_bounds__(NT, 8) void despawn_kernel(
    const float* __restrict__ x,
    const float* __restrict__ scaling,
    const float* __restrict__ scaling_rec,
    float* __restrict__ recon_out,
    float* __restrict__ coef_out)
{
    __shared__ __align__(16) float SA[2048];   // 8 KB
    __shared__ __align__(16) float SB[2176];   // 8.5 KB (staging needs 2116)
    __shared__ __align__(16) float CS[512];    // 2 KB: details lvl>=3 + final approx

    const int tid = threadIdx.x;
    const int row = blockIdx.x;
    float* const crow = coef_out + (size_t)row * LPAD;
    const float* xr = x + (size_t)row * MLEN;

    // Desync co-resident blocks (CU-mates are blockIdx stride-8: consecutive ids
    // round-robin across the 8 XCDs). Breaks barrier lockstep so one block's
    // phase-latency overlaps another's compute. ~0-1.5K cyc, 4-way stagger.
    {
        const int lag = (blockIdx.x >> 3) & 3;
        for (int i = 0; i < lag; ++i) __builtin_amdgcn_s_sleep(8);
    }

    // ---------------- analysis level 0 : two halves through SB ----------------
    // out[j] = sum_k x_pad[(2j-k) mod 4096] f[k]; x_pad[i]=xr[clamp(i-548)], i<0 wraps->xhi
    for (int h = 0; h < 2; ++h) {
        const int j0 = 1024 * h;
        // stage naturals [2*j0-8, 2*j0+2048): ev[c] at SB[4+c], od[c] at SB[1088+4+c]
        for (int gi = tid; gi < 514; gi += NT) {
            const int n0 = 2 * j0 - 8 + 4 * gi;
            F4 u;
            if (n0 >= PAD0 && n0 + 3 <= PAD0 + MLEN - 1) {
                u.v = *reinterpret_cast<const float4*>(xr + (n0 - PAD0));
            } else {
#pragma unroll
                for (int e = 0; e < 4; ++e) {
                    int n = n0 + e;
                    if (n < 0) n += LPAD;                 // circular wrap into hi pad
                    int g = n - PAD0;
                    g = g < 0 ? 0 : (g > MLEN - 1 ? MLEN - 1 : g);
                    u.f[e] = xr[g];
                }
            }
            *reinterpret_cast<float2*>(&SB[2 * gi])        = make_float2(u.f[0], u.f[2]);
            *reinterpret_cast<float2*>(&SB[1088 + 2 * gi]) = make_float2(u.f[1], u.f[3]);
        }
        lds_barrier();
        {
            float S[8], Wr[8];
#pragma unroll
            for (int k = 0; k < 8; ++k) { S[k] = scaling[k]; Wr[k] = scaling_rec[7 - k]; }
            const float4* ev4 = reinterpret_cast<const float4*>(&SB[0]);
            const float4* od4 = reinterpret_cast<const float4*>(&SB[1088]);
            float4* dst4 = reinterpret_cast<float4*>(crow + j0);
            const int t = tid;                 // 256 items, 4 outputs each
            F4 Ea, Eb, Oa, Ob;
            Ea.v = ev4[t];     // ev c = 4t-4..4t-1
            Eb.v = ev4[t + 1]; // ev c = 4t..4t+3
            Oa.v = od4[t];
            Ob.v = od4[t + 1];
            float e[8] = {Ea.f[0],Ea.f[1],Ea.f[2],Ea.f[3],Eb.f[0],Eb.f[1],Eb.f[2],Eb.f[3]};
            float o[8] = {Oa.f[0],Oa.f[1],Oa.f[2],Oa.f[3],Ob.f[0],Ob.f[1],Ob.f[2],Ob.f[3]};
            float ds[4], as[4];
            __builtin_amdgcn_s_setprio(1);
#pragma unroll
            for (int u = 0; u < 4; ++u) {
                float d = 0.f, a = 0.f;
#pragma unroll
                for (int m = 0; m < 4; ++m) {
                    const float vE = e[4 + u - m];
                    const float vO = o[3 + u - m];
                    d = fmaf(vE, Wr[2 * m], d);
                    d = fmaf(vO, -Wr[2 * m + 1], d);
                    a = fmaf(vE, S[2 * m], a);
                    a = fmaf(vO, S[2 * m + 1], a);
                }
                ds[u] = d; as[u] = a;
            }
            __builtin_amdgcn_s_setprio(0);
            F4 dv; dv.f[0] = ds[0]; dv.f[1] = ds[1]; dv.f[2] = ds[2]; dv.f[3] = ds[3];
            dst4[t] = dv.v;                                  // details0 -> global
            *reinterpret_cast<float2*>(SA + (j0 >> 1) + 2 * t)        = make_float2(as[0], as[2]);
            *reinterpret_cast<float2*>(SA + 1024 + (j0 >> 1) + 2 * t) = make_float2(as[1], as[3]);
        }
        lds_barrier();
    }

    // ---------------- analysis levels 1..7 : LDS ping-pong ----------------
    {
        float* cur = SA;
        float* alt = SB;
        int H = 1024;
        int coff = 2048;
        for (int lvl = 1; lvl < NLVL; ++lvl) {
            float S[8], Wr[8];
#pragma unroll
            for (int k = 0; k < 8; ++k) {
                S[k]  = scaling[lvl * 8 + k];
                Wr[k] = scaling_rec[lvl * 8 + 7 - k];
            }
            const int q = H >> 2;
            const int qm = q - 1;
            const float4* ev4 = reinterpret_cast<const float4*>(cur);
            const float4* od4 = reinterpret_cast<const float4*>(cur + H);
            float4* dst4 = reinterpret_cast<float4*>(crow + coff);
            float4* mir4 = (lvl == 1) ? reinterpret_cast<float4*>(&SB[1088])
                         : (lvl == 2) ? reinterpret_cast<float4*>(&SA[512])
                                      : reinterpret_cast<float4*>(&CS[coff - 3584]);
            for (int t = tid; t < q; t += NT) {
                F4 Ea, Eb, Oa, Ob;
                Ea.v = ev4[(t - 1) & qm];
                Eb.v = ev4[t];
                Oa.v = od4[(t - 1) & qm];
                Ob.v = od4[t];
                float e[8] = {Ea.f[0],Ea.f[1],Ea.f[2],Ea.f[3],Eb.f[0],Eb.f[1],Eb.f[2],Eb.f[3]};
                float o[8] = {Oa.f[0],Oa.f[1],Oa.f[2],Oa.f[3],Ob.f[0],Ob.f[1],Ob.f[2],Ob.f[3]};
                float ds[4], as[4];
                __builtin_amdgcn_s_setprio(1);
#pragma unroll
                for (int u = 0; u < 4; ++u) {
                    float d = 0.f, a = 0.f;
#pragma unroll
                    for (int m = 0; m < 4; ++m) {
                        const float vE = e[4 + u - m];
                        const float vO = o[3 + u - m];
                        d = fmaf(vE, Wr[2 * m], d);
                        d = fmaf(vO, -Wr[2 * m + 1], d);
                        a = fmaf(vE, S[2 * m], a);
                        a = fmaf(vO, S[2 * m + 1], a);
                    }
                    ds[u] = d; as[u] = a;
                }
                __builtin_amdgcn_s_setprio(0);
                F4 dv; dv.f[0] = ds[0]; dv.f[1] = ds[1]; dv.f[2] = ds[2]; dv.f[3] = ds[3];
                dst4[t] = dv.v;      // details -> global (coeffs output), not drained
                mir4[t] = dv.v;      // details -> LDS mirror for synthesis
                *reinterpret_cast<float2*>(alt + 2 * t)            = make_float2(as[0], as[2]);
                *reinterpret_cast<float2*>(alt + (H >> 1) + 2 * t) = make_float2(as[1], as[3]);
            }
            lds_barrier();
            coff += H;
            float* tmp = cur; cur = alt; alt = tmp;
            H >>= 1;
        }
    }

    // final approx (split, 16) in SB -> natural order to crow tail + CS tail
    if (tid < 16) {
        const float v = SB[((tid & 1) ? 8 : 0) + (tid >> 1)];
        crow[LPAD - 16 + tid] = v;
        CS[496 + tid] = v;
    }
    // FULL sync: drains every wave's crow stores before synthesis's global
    // readback of details0 (the one place vmcnt(0) is semantically required).
    __syncthreads();

    // ---------------- synthesis levels 7..1 (all-LDS) ----------------
    // out[n] = sum_{k≡n mod 2} d[((n+p)/2+m)&lm]*wav[k] + a[..]*sca[k], k=p+2m
    // wav sign (-1)^k with k=p+2m -> (p ? -1 : +1), folded per-u.
    const float* a = &CS[496];
    float* obuf = SA;   // 32->SA,64->SB,128->SA,256->SB,512->SA,1024->SB,2048->SA
    int len = 16;
    for (int lvl = NLVL - 1; lvl >= 1; --lvl) {
        float S[8], Wr[8];
#pragma unroll
        for (int k = 0; k < 8; ++k) {
            S[k]  = scaling[lvl * 8 + k];
            Wr[k] = scaling_rec[lvl * 8 + 7 - k];
        }
        const int Mout = len << 1;
        const int doff = LPAD - (LPAD >> lvl);
        const float4* d4 = (lvl >= 3) ? reinterpret_cast<const float4*>(&CS[doff - 3584])
                         : (lvl == 2) ? reinterpret_cast<const float4*>(&SA[512])
                                      : reinterpret_cast<const float4*>(&SB[1088]);
        const float4* a4 = reinterpret_cast<const float4*>(a);
        const int gq = Mout >> 3;     // 8 outputs per work item
        const int fm = (len >> 2) - 1;
        for (int g = tid; g < gq; g += NT) {
            F4 Da, Db, Aa, Ab;
            Da.v = d4[g]; Db.v = d4[(g + 1) & fm];
            Aa.v = a4[g]; Ab.v = a4[(g + 1) & fm];
            float dd[8] = {Da.f[0],Da.f[1],Da.f[2],Da.f[3],Db.f[0],Db.f[1],Db.f[2],Db.f[3]};
            float aa[8] = {Aa.f[0],Aa.f[1],Aa.f[2],Aa.f[3],Ab.f[0],Ab.f[1],Ab.f[2],Ab.f[3]};
            float out[8];
            __builtin_amdgcn_s_setprio(1);
#pragma unroll
            for (int u = 0; u < 8; ++u) {
                const int p = u & 1, c = (u + 1) >> 1;
                float s = 0.f;
#pragma unroll
                for (int m = 0; m < 4; ++m) {
                    const float w = Wr[p + 2 * m];
                    s = fmaf(dd[c + m], p ? -w : w, s);
                    s = fmaf(aa[c + m], S[p + 2 * m], s);
                }
                out[u] = s;
            }
            __builtin_amdgcn_s_setprio(0);
            F4 o0, o1;
            o0.f[0] = out[0]; o0.f[1] = out[1]; o0.f[2] = out[2]; o0.f[3] = out[3];
            o1.f[0] = out[4]; o1.f[1] = out[5]; o1.f[2] = out[6]; o1.f[3] = out[7];
            float4* ob4 = reinterpret_cast<float4*>(obuf + 8 * g);
            ob4[0] = o0.v; ob4[1] = o1.v;
        }
        lds_barrier();
        a = obuf;
        obuf = (obuf == SA) ? SB : SA;
        len = Mout;
    }
    // a == SA (2048 approx)

    // ---------------- synthesis level 0 : straight to recon ----------------
    {
        float S[8], Wr[8];
#pragma unroll
        for (int k = 0; k < 8; ++k) { S[k] = scaling[k]; Wr[k] = scaling_rec[7 - k]; }
        const float4* d4 = reinterpret_cast<const float4*>(crow);   // details0 (L2-warm)
        const float4* a4 = reinterpret_cast<const float4*>(a);
        const int fm = (len >> 2) - 1;                              // len == 2048
        float* const ro = recon_out + (size_t)row * MLEN;
        for (int g = tid; g < (LPAD >> 3); g += NT) {
            F4 Da, Db, Aa, Ab;
            Da.v = d4[g]; Db.v = d4[(g + 1) & fm];
            Aa.v = a4[g]; Ab.v = a4[(g + 1) & fm];
            float dd[8] = {Da.f[0],Da.f[1],Da.f[2],Da.f[3],Db.f[0],Db.f[1],Db.f[2],Db.f[3]};
            float aa[8] = {Aa.f[0],Aa.f[1],Aa.f[2],Aa.f[3],Ab.f[0],Ab.f[1],Ab.f[2],Ab.f[3]};
            float out[8];
            __builtin_amdgcn_s_setprio(1);
#pragma unroll
            for (int u = 0; u < 8; ++u) {
                const int p = u & 1, c = (u + 1) >> 1;
                float s = 0.f;
#pragma unroll
                for (int m = 0; m < 4; ++m) {
                    const float w = Wr[p + 2 * m];
                    s = fmaf(dd[c + m], p ? -w : w, s);
                    s = fmaf(aa[c + m], S[p + 2 * m], s);
                }
                out[u] = s;
            }
            __builtin_amdgcn_s_setprio(0);
            const int n0 = 8 * g;
            if (n0 >= PAD0 && n0 + 8 <= PAD0 + MLEN) {
                F4 o0, o1;
                o0.f[0] = out[0]; o0.f[1] = out[1]; o0.f[2] = out[2]; o0.f[3] = out[3];
                o1.f[0] = out[4]; o1.f[1] = out[5]; o1.f[2] = out[6]; o1.f[3] = out[7];
                float4* r4 = reinterpret_cast<float4*>(ro + (n0 - PAD0));
                r4[0] = o0.v; r4[1] = o1.v;
            } else {
#pragma unroll
                for (int u = 0; u < 8; ++u) {
                    const int n = n0 + u;
                    if (n >= PAD0 && n < PAD0 + MLEN) ro[n - PAD0] = out[u];
                }
            }
        }
    }
}

extern "C" void kernel_launch(void* const* d_in, const int* in_sizes, int n_in,
                              void* d_out, int out_size, void* d_ws, size_t ws_size,
                              hipStream_t stream) {
    const float* x           = (const float*)d_in[0];
    const float* scaling     = (const float*)d_in[1];
    const float* scaling_rec = (const float*)d_in[2];
    float* recon = (float*)d_out;                       // 2048*3000 floats
    float* coefo = recon + (size_t)NROWS * MLEN;        // 2048*4096 floats
    despawn_kernel<<<dim3(NROWS), dim3(NT), 0, stream>>>(x, scaling, scaling_rec,
                                                         recon, coefo);
    (void)in_sizes; (void)n_in; (void)out_size; (void)d_ws; (void)ws_size;
}

// Round 4
// 95.704 us; speedup vs baseline: 1.0265x; 1.0265x over previous
//
#include <hip/hip_runtime.h>

#define NROWS 2048
#define MLEN  3000
#define LPAD  4096
#define PAD0  548
#define NLVL  8
#define NT    256

union F4 { float4 v; float f[4]; };

// Light barrier: LDS-visibility only (s_waitcnt lgkmcnt(0) + s_barrier).
// Does NOT drain vmcnt, so details->global write-through stays in flight
// across analysis level boundaries.
__device__ inline void lds_barrier() {
    asm volatile("s_waitcnt lgkmcnt(0)\n\ts_barrier" ::: "memory");
}

// LDS 18.25KB (SA 8K + SB 8.25K + CS 2K) -> 8 blocks/CU, 32 waves.
// R6: s_setprio(1) around FMA bursts (T5).
// R7: filters in SGPRs (s_load from global at wave-uniform indices; wavelet
//     sign folded into fmaf neg modifier, 7-k reversal into indexing).
// R8: analysis lvl0 reads x DIRECTLY from global (4x dwordx4 per thread,
//     in-register even/odd deinterleave) — deletes the staging loop, the
//     SB round-trip and 3 of lvl0's 4 barriers. All out-of-range elements
//     are constants (x[0] / x[2999], incl. the circular-wrap region) ->
//     selects, not gathers. Also folds the tid<16 final-approx repack into
//     analysis lvl7 (natural-order float4 to CS tail + crow tail).
// Barrier phases: 20 -> 16.
__global__ __launch_bounds__(NT, 8) void despawn_kernel(
    const float* __restrict__ x,
    const float* __restrict__ scaling,
    const float* __restrict__ scaling_rec,
    float* __restrict__ recon_out,
    float* __restrict__ coef_out)
{
    __shared__ __align__(16) float SA[2048];   // 8 KB
    __shared__ __align__(16) float SB[2112];   // 8.25 KB (lvl1 alt + lvl1 mirror)
    __shared__ __align__(16) float CS[512];    // 2 KB: details lvl>=3 + final approx

    const int tid = threadIdx.x;
    const int row = blockIdx.x;
    float* const crow = coef_out + (size_t)row * LPAD;
    const float* xr = x + (size_t)row * MLEN;

    // Desync co-resident blocks (CU-mates are blockIdx stride-8: consecutive ids
    // round-robin across the 8 XCDs). Breaks barrier lockstep so one block's
    // phase-latency overlaps another's compute. ~0-1.5K cyc, 4-way stagger.
    {
        const int lag = (blockIdx.x >> 3) & 3;
        for (int i = 0; i < lag; ++i) __builtin_amdgcn_s_sleep(8);
    }

    // ---------------- analysis level 0 : direct from global ----------------
    // out[j] = sum_k x_pad[(2j-k) mod 4096] f[k]; x_pad[i]=xr[clamp(i-548)],
    // i<0 wraps to hi pad (also clamps to xr[2999]).
    // Thread t, half h needs naturals [2j0+8t-8, 2j0+8t+7] (16B-aligned in xr).
    {
        float S[8], Wr[8];
#pragma unroll
        for (int k = 0; k < 8; ++k) { S[k] = scaling[k]; Wr[k] = scaling_rec[7 - k]; }
#pragma unroll
        for (int h = 0; h < 2; ++h) {
            const int j0 = 1024 * h;
            const int n0 = 2 * j0 + 8 * tid - 8;
            F4 V0, V1, V2, V3;
            if (n0 >= PAD0 && n0 + 15 <= PAD0 + MLEN - 1) {
                const float4* src = reinterpret_cast<const float4*>(xr + (n0 - PAD0));
                V0.v = src[0]; V1.v = src[1]; V2.v = src[2]; V3.v = src[3];
            } else {
                const float x0  = xr[0];
                const float xhi = xr[MLEN - 1];
#pragma unroll
                for (int j = 0; j < 16; ++j) {
                    const int n = n0 + j;
                    const int m = (n < 0) ? n + LPAD : n;   // wrap region is all >= 3548
                    float val;
                    if (m < PAD0)             val = x0;
                    else if (m >= PAD0 + MLEN) val = xhi;
                    else                       val = xr[m - PAD0];
                    if (j < 4)       V0.f[j & 3] = val;
                    else if (j < 8)  V1.f[j & 3] = val;
                    else if (j < 12) V2.f[j & 3] = val;
                    else             V3.f[j & 3] = val;
                }
            }
            float e[8] = {V0.f[0],V0.f[2],V1.f[0],V1.f[2],V2.f[0],V2.f[2],V3.f[0],V3.f[2]};
            float o[8] = {V0.f[1],V0.f[3],V1.f[1],V1.f[3],V2.f[1],V2.f[3],V3.f[1],V3.f[3]};
            float ds[4], as[4];
            __builtin_amdgcn_s_setprio(1);
#pragma unroll
            for (int u = 0; u < 4; ++u) {
                float d = 0.f, a = 0.f;
#pragma unroll
                for (int m = 0; m < 4; ++m) {
                    const float vE = e[4 + u - m];
                    const float vO = o[3 + u - m];
                    d = fmaf(vE, Wr[2 * m], d);
                    d = fmaf(vO, -Wr[2 * m + 1], d);
                    a = fmaf(vE, S[2 * m], a);
                    a = fmaf(vO, S[2 * m + 1], a);
                }
                ds[u] = d; as[u] = a;
            }
            __builtin_amdgcn_s_setprio(0);
            F4 dv; dv.f[0] = ds[0]; dv.f[1] = ds[1]; dv.f[2] = ds[2]; dv.f[3] = ds[3];
            reinterpret_cast<float4*>(crow + j0)[tid] = dv.v;    // details0 -> global
            *reinterpret_cast<float2*>(SA + (j0 >> 1) + 2 * tid)        = make_float2(as[0], as[2]);
            *reinterpret_cast<float2*>(SA + 1024 + (j0 >> 1) + 2 * tid) = make_float2(as[1], as[3]);
        }
    }
    lds_barrier();   // SA (approx0, split ev|od) complete

    // ---------------- analysis levels 1..7 : LDS ping-pong ----------------
    {
        float* cur = SA;
        float* alt = SB;
        int H = 1024;
        int coff = 2048;
        for (int lvl = 1; lvl < NLVL; ++lvl) {
            float S[8], Wr[8];
#pragma unroll
            for (int k = 0; k < 8; ++k) {
                S[k]  = scaling[lvl * 8 + k];
                Wr[k] = scaling_rec[lvl * 8 + 7 - k];
            }
            const int q = H >> 2;
            const int qm = q - 1;
            const float4* ev4 = reinterpret_cast<const float4*>(cur);
            const float4* od4 = reinterpret_cast<const float4*>(cur + H);
            float4* dst4 = reinterpret_cast<float4*>(crow + coff);
            float4* mir4 = (lvl == 1) ? reinterpret_cast<float4*>(&SB[1088])
                         : (lvl == 2) ? reinterpret_cast<float4*>(&SA[512])
                                      : reinterpret_cast<float4*>(&CS[coff - 3584]);
            for (int t = tid; t < q; t += NT) {
                F4 Ea, Eb, Oa, Ob;
                Ea.v = ev4[(t - 1) & qm];
                Eb.v = ev4[t];
                Oa.v = od4[(t - 1) & qm];
                Ob.v = od4[t];
                float e[8] = {Ea.f[0],Ea.f[1],Ea.f[2],Ea.f[3],Eb.f[0],Eb.f[1],Eb.f[2],Eb.f[3]};
                float o[8] = {Oa.f[0],Oa.f[1],Oa.f[2],Oa.f[3],Ob.f[0],Ob.f[1],Ob.f[2],Ob.f[3]};
                float ds[4], as[4];
                __builtin_amdgcn_s_setprio(1);
#pragma unroll
                for (int u = 0; u < 4; ++u) {
                    float d = 0.f, a = 0.f;
#pragma unroll
                    for (int m = 0; m < 4; ++m) {
                        const float vE = e[4 + u - m];
                        const float vO = o[3 + u - m];
                        d = fmaf(vE, Wr[2 * m], d);
                        d = fmaf(vO, -Wr[2 * m + 1], d);
                        a = fmaf(vE, S[2 * m], a);
                        a = fmaf(vO, S[2 * m + 1], a);
                    }
                    ds[u] = d; as[u] = a;
                }
                __builtin_amdgcn_s_setprio(0);
                F4 dv; dv.f[0] = ds[0]; dv.f[1] = ds[1]; dv.f[2] = ds[2]; dv.f[3] = ds[3];
                dst4[t] = dv.v;      // details -> global (coeffs output), not drained
                mir4[t] = dv.v;      // details -> LDS mirror for synthesis
                if (lvl < NLVL - 1) {
                    *reinterpret_cast<float2*>(alt + 2 * t)            = make_float2(as[0], as[2]);
                    *reinterpret_cast<float2*>(alt + (H >> 1) + 2 * t) = make_float2(as[1], as[3]);
                } else {
                    // final approx: natural order (split alt[2t]=approx[4t],
                    // alt[H/2+2t]=approx[4t+1] ... => as[u]=approx[4t+u])
                    F4 av; av.f[0] = as[0]; av.f[1] = as[1]; av.f[2] = as[2]; av.f[3] = as[3];
                    *reinterpret_cast<float4*>(&CS[496 + 4 * t])         = av.v;
                    *reinterpret_cast<float4*>(crow + LPAD - 16 + 4 * t) = av.v;
                }
            }
            lds_barrier();
            coff += H;
            float* tmp = cur; cur = alt; alt = tmp;
            H >>= 1;
        }
    }

    // FULL sync: drains every wave's crow stores before synthesis's global
    // readback of details0 (the one place vmcnt(0) is semantically required).
    __syncthreads();

    // ---------------- synthesis levels 7..1 (all-LDS) ----------------
    // out[n] = sum_{k≡n mod 2} d[((n+p)/2+m)&lm]*wav[k] + a[..]*sca[k], k=p+2m
    // wav sign (-1)^k with k=p+2m -> (p ? -1 : +1), folded per-u.
    const float* a = &CS[496];
    float* obuf = SA;   // 32->SA,64->SB,128->SA,256->SB,512->SA,1024->SB,2048->SA
    int len = 16;
    for (int lvl = NLVL - 1; lvl >= 1; --lvl) {
        float S[8], Wr[8];
#pragma unroll
        for (int k = 0; k < 8; ++k) {
            S[k]  = scaling[lvl * 8 + k];
            Wr[k] = scaling_rec[lvl * 8 + 7 - k];
        }
        const int Mout = len << 1;
        const int doff = LPAD - (LPAD >> lvl);
        const float4* d4 = (lvl >= 3) ? reinterpret_cast<const float4*>(&CS[doff - 3584])
                         : (lvl == 2) ? reinterpret_cast<const float4*>(&SA[512])
                                      : reinterpret_cast<const float4*>(&SB[1088]);
        const float4* a4 = reinterpret_cast<const float4*>(a);
        const int gq = Mout >> 3;     // 8 outputs per work item
        const int fm = (len >> 2) - 1;
        for (int g = tid; g < gq; g += NT) {
            F4 Da, Db, Aa, Ab;
            Da.v = d4[g]; Db.v = d4[(g + 1) & fm];
            Aa.v = a4[g]; Ab.v = a4[(g + 1) & fm];
            float dd[8] = {Da.f[0],Da.f[1],Da.f[2],Da.f[3],Db.f[0],Db.f[1],Db.f[2],Db.f[3]};
            float aa[8] = {Aa.f[0],Aa.f[1],Aa.f[2],Aa.f[3],Ab.f[0],Ab.f[1],Ab.f[2],Ab.f[3]};
            float out[8];
            __builtin_amdgcn_s_setprio(1);
#pragma unroll
            for (int u = 0; u < 8; ++u) {
                const int p = u & 1, c = (u + 1) >> 1;
                float s = 0.f;
#pragma unroll
                for (int m = 0; m < 4; ++m) {
                    const float w = Wr[p + 2 * m];
                    s = fmaf(dd[c + m], p ? -w : w, s);
                    s = fmaf(aa[c + m], S[p + 2 * m], s);
                }
                out[u] = s;
            }
            __builtin_amdgcn_s_setprio(0);
            F4 o0, o1;
            o0.f[0] = out[0]; o0.f[1] = out[1]; o0.f[2] = out[2]; o0.f[3] = out[3];
            o1.f[0] = out[4]; o1.f[1] = out[5]; o1.f[2] = out[6]; o1.f[3] = out[7];
            float4* ob4 = reinterpret_cast<float4*>(obuf + 8 * g);
            ob4[0] = o0.v; ob4[1] = o1.v;
        }
        lds_barrier();
        a = obuf;
        obuf = (obuf == SA) ? SB : SA;
        len = Mout;
    }
    // a == SA (2048 approx)

    // ---------------- synthesis level 0 : straight to recon ----------------
    {
        float S[8], Wr[8];
#pragma unroll
        for (int k = 0; k < 8; ++k) { S[k] = scaling[k]; Wr[k] = scaling_rec[7 - k]; }
        const float4* d4 = reinterpret_cast<const float4*>(crow);   // details0 (L2-warm)
        const float4* a4 = reinterpret_cast<const float4*>(a);
        const int fm = (len >> 2) - 1;                              // len == 2048
        float* const ro = recon_out + (size_t)row * MLEN;
        for (int g = tid; g < (LPAD >> 3); g += NT) {
            F4 Da, Db, Aa, Ab;
            Da.v = d4[g]; Db.v = d4[(g + 1) & fm];
            Aa.v = a4[g]; Ab.v = a4[(g + 1) & fm];
            float dd[8] = {Da.f[0],Da.f[1],Da.f[2],Da.f[3],Db.f[0],Db.f[1],Db.f[2],Db.f[3]};
            float aa[8] = {Aa.f[0],Aa.f[1],Aa.f[2],Aa.f[3],Ab.f[0],Ab.f[1],Ab.f[2],Ab.f[3]};
            float out[8];
            __builtin_amdgcn_s_setprio(1);
#pragma unroll
            for (int u = 0; u < 8; ++u) {
                const int p = u & 1, c = (u + 1) >> 1;
                float s = 0.f;
#pragma unroll
                for (int m = 0; m < 4; ++m) {
                    const float w = Wr[p + 2 * m];
                    s = fmaf(dd[c + m], p ? -w : w, s);
                    s = fmaf(aa[c + m], S[p + 2 * m], s);
                }
                out[u] = s;
            }
            __builtin_amdgcn_s_setprio(0);
            const int n0 = 8 * g;
            if (n0 >= PAD0 && n0 + 8 <= PAD0 + MLEN) {
                F4 o0, o1;
                o0.f[0] = out[0]; o0.f[1] = out[1]; o0.f[2] = out[2]; o0.f[3] = out[3];
                o1.f[0] = out[4]; o1.f[1] = out[5]; o1.f[2] = out[6]; o1.f[3] = out[7];
                float4* r4 = reinterpret_cast<float4*>(ro + (n0 - PAD0));
                r4[0] = o0.v; r4[1] = o1.v;
            } else {
#pragma unroll
                for (int u = 0; u < 8; ++u) {
                    const int n = n0 + u;
                    if (n >= PAD0 && n < PAD0 + MLEN) ro[n - PAD0] = out[u];
                }
            }
        }
    }
}

extern "C" void kernel_launch(void* const* d_in, const int* in_sizes, int n_in,
                              void* d_out, int out_size, void* d_ws, size_t ws_size,
                              hipStream_t stream) {
    const float* x           = (const float*)d_in[0];
    const float* scaling     = (const float*)d_in[1];
    const float* scaling_rec = (const float*)d_in[2];
    float* recon = (float*)d_out;                       // 2048*3000 floats
    float* coefo = recon + (size_t)NROWS * MLEN;        // 2048*4096 floats
    despawn_kernel<<<dim3(NROWS), dim3(NT), 0, stream>>>(x, scaling, scaling_rec,
                                                         recon, coefo);
    (void)in_sizes; (void)n_in; (void)out_size; (void)d_ws; (void)ws_size;
}

// Round 5
// 95.267 us; speedup vs baseline: 1.0312x; 1.0046x over previous
//
#include <hip/hip_runtime.h>

#define NROWS 2048
#define MLEN  3000
#define LPAD  4096
#define PAD0  548
#define NLVL  8
#define NT    512
#define RPB   2

union F4 { float4 v; float f[4]; };

// Light barrier: LDS-visibility only (s_waitcnt lgkmcnt(0) + s_barrier).
// Does NOT drain vmcnt, so details->global write-through stays in flight
// across analysis level boundaries.
__device__ inline void lds_barrier() {
    asm volatile("s_waitcnt lgkmcnt(0)\n\ts_barrier" ::: "memory");
}

// R6: s_setprio(1) around FMA bursts (T5).
// R7: filters in SGPRs (s_load from global at wave-uniform indices; wavelet
//     sign folded into fmaf neg modifier, 7-k reversal into indexing).
// R8: analysis lvl0 reads x directly from global (4x dwordx4/thread,
//     in-register even/odd deinterleave); final-approx repack folded into lvl7.
// R9: TWO ROWS PER BLOCK at constant wave count — NT=512, grid=1024,
//     LDS 2x18.25KB=36.5KB -> 4 blocks/CU x 8 waves = 32 waves/CU (same as
//     before, = 2048-thread cap). tid>>8 selects row; each 256-thread half
//     runs the per-row pipeline on its own LDS slice. Barrier-chain instances
//     per CU halve (8->4); per-phase issued work doubles; total work constant.
__global__ __launch_bounds__(NT, 8) void despawn_kernel(
    const float* __restrict__ x,
    const float* __restrict__ scaling,
    const float* __restrict__ scaling_rec,
    float* __restrict__ recon_out,
    float* __restrict__ coef_out)
{
    // per row: SA 2048 | SB 2112 | CS 512  (4672 floats = 18688 B)
    __shared__ __align__(16) float LDSBUF[RPB][4672];

    const int tid = threadIdx.x;
    const int r   = tid >> 8;        // row slot within block
    const int t   = tid & 255;       // lane within row pipeline
    const int row = blockIdx.x * RPB + r;
    float* const sa = &LDSBUF[r][0];
    float* const sb = &LDSBUF[r][2048];
    float* const cs = &LDSBUF[r][4160];

    float* const crow = coef_out + (size_t)row * LPAD;
    const float* xr = x + (size_t)row * MLEN;

    // Desync co-resident blocks (consecutive ids round-robin across 8 XCDs).
    {
        const int lag = (blockIdx.x >> 3) & 3;
        for (int i = 0; i < lag; ++i) __builtin_amdgcn_s_sleep(8);
    }

    // ---------------- analysis level 0 : direct from global ----------------
    // out[j] = sum_k x_pad[(2j-k) mod 4096] f[k]; x_pad[i]=xr[clamp(i-548)],
    // i<0 wraps to hi pad (also clamps to xr[2999]).
    // Thread t, half h needs naturals [2j0+8t-8, 2j0+8t+7] (16B-aligned in xr).
    {
        float S[8], Wr[8];
#pragma unroll
        for (int k = 0; k < 8; ++k) { S[k] = scaling[k]; Wr[k] = scaling_rec[7 - k]; }
#pragma unroll
        for (int h = 0; h < 2; ++h) {
            const int j0 = 1024 * h;
            const int n0 = 2 * j0 + 8 * t - 8;
            F4 V0, V1, V2, V3;
            if (n0 >= PAD0 && n0 + 15 <= PAD0 + MLEN - 1) {
                const float4* src = reinterpret_cast<const float4*>(xr + (n0 - PAD0));
                V0.v = src[0]; V1.v = src[1]; V2.v = src[2]; V3.v = src[3];
            } else {
                const float x0  = xr[0];
                const float xhi = xr[MLEN - 1];
#pragma unroll
                for (int j = 0; j < 16; ++j) {
                    const int n = n0 + j;
                    const int m = (n < 0) ? n + LPAD : n;   // wrap region is all >= 3548
                    float val;
                    if (m < PAD0)              val = x0;
                    else if (m >= PAD0 + MLEN) val = xhi;
                    else                       val = xr[m - PAD0];
                    if (j < 4)       V0.f[j & 3] = val;
                    else if (j < 8)  V1.f[j & 3] = val;
                    else if (j < 12) V2.f[j & 3] = val;
                    else             V3.f[j & 3] = val;
                }
            }
            float e[8] = {V0.f[0],V0.f[2],V1.f[0],V1.f[2],V2.f[0],V2.f[2],V3.f[0],V3.f[2]};
            float o[8] = {V0.f[1],V0.f[3],V1.f[1],V1.f[3],V2.f[1],V2.f[3],V3.f[1],V3.f[3]};
            float ds[4], as[4];
            __builtin_amdgcn_s_setprio(1);
#pragma unroll
            for (int u = 0; u < 4; ++u) {
                float d = 0.f, a = 0.f;
#pragma unroll
                for (int m = 0; m < 4; ++m) {
                    const float vE = e[4 + u - m];
                    const float vO = o[3 + u - m];
                    d = fmaf(vE, Wr[2 * m], d);
                    d = fmaf(vO, -Wr[2 * m + 1], d);
                    a = fmaf(vE, S[2 * m], a);
                    a = fmaf(vO, S[2 * m + 1], a);
                }
                ds[u] = d; as[u] = a;
            }
            __builtin_amdgcn_s_setprio(0);
            F4 dv; dv.f[0] = ds[0]; dv.f[1] = ds[1]; dv.f[2] = ds[2]; dv.f[3] = ds[3];
            reinterpret_cast<float4*>(crow + j0)[t] = dv.v;      // details0 -> global
            *reinterpret_cast<float2*>(sa + (j0 >> 1) + 2 * t)        = make_float2(as[0], as[2]);
            *reinterpret_cast<float2*>(sa + 1024 + (j0 >> 1) + 2 * t) = make_float2(as[1], as[3]);
        }
    }
    lds_barrier();   // sa (approx0, split ev|od) complete for both rows

    // ---------------- analysis levels 1..7 : LDS ping-pong ----------------
    {
        float* cur = sa;
        float* alt = sb;
        int H = 1024;
        int coff = 2048;
        for (int lvl = 1; lvl < NLVL; ++lvl) {
            float S[8], Wr[8];
#pragma unroll
            for (int k = 0; k < 8; ++k) {
                S[k]  = scaling[lvl * 8 + k];
                Wr[k] = scaling_rec[lvl * 8 + 7 - k];
            }
            const int q = H >> 2;
            const int qm = q - 1;
            const float4* ev4 = reinterpret_cast<const float4*>(cur);
            const float4* od4 = reinterpret_cast<const float4*>(cur + H);
            float4* dst4 = reinterpret_cast<float4*>(crow + coff);
            float4* mir4 = (lvl == 1) ? reinterpret_cast<float4*>(sb + 1088)
                         : (lvl == 2) ? reinterpret_cast<float4*>(sa + 512)
                                      : reinterpret_cast<float4*>(cs + (coff - 3584));
            for (int tt = t; tt < q; tt += 256) {
                F4 Ea, Eb, Oa, Ob;
                Ea.v = ev4[(tt - 1) & qm];
                Eb.v = ev4[tt];
                Oa.v = od4[(tt - 1) & qm];
                Ob.v = od4[tt];
                float e[8] = {Ea.f[0],Ea.f[1],Ea.f[2],Ea.f[3],Eb.f[0],Eb.f[1],Eb.f[2],Eb.f[3]};
                float o[8] = {Oa.f[0],Oa.f[1],Oa.f[2],Oa.f[3],Ob.f[0],Ob.f[1],Ob.f[2],Ob.f[3]};
                float ds[4], as[4];
                __builtin_amdgcn_s_setprio(1);
#pragma unroll
                for (int u = 0; u < 4; ++u) {
                    float d = 0.f, a = 0.f;
#pragma unroll
                    for (int m = 0; m < 4; ++m) {
                        const float vE = e[4 + u - m];
                        const float vO = o[3 + u - m];
                        d = fmaf(vE, Wr[2 * m], d);
                        d = fmaf(vO, -Wr[2 * m + 1], d);
                        a = fmaf(vE, S[2 * m], a);
                        a = fmaf(vO, S[2 * m + 1], a);
                    }
                    ds[u] = d; as[u] = a;
                }
                __builtin_amdgcn_s_setprio(0);
                F4 dv; dv.f[0] = ds[0]; dv.f[1] = ds[1]; dv.f[2] = ds[2]; dv.f[3] = ds[3];
                dst4[tt] = dv.v;     // details -> global (coeffs output), not drained
                mir4[tt] = dv.v;     // details -> LDS mirror for synthesis
                if (lvl < NLVL - 1) {
                    *reinterpret_cast<float2*>(alt + 2 * tt)            = make_float2(as[0], as[2]);
                    *reinterpret_cast<float2*>(alt + (H >> 1) + 2 * tt) = make_float2(as[1], as[3]);
                } else {
                    // final approx in natural order (as[u]=approx[4tt+u])
                    F4 av; av.f[0] = as[0]; av.f[1] = as[1]; av.f[2] = as[2]; av.f[3] = as[3];
                    *reinterpret_cast<float4*>(cs + 496 + 4 * tt)         = av.v;
                    *reinterpret_cast<float4*>(crow + LPAD - 16 + 4 * tt) = av.v;
                }
            }
            lds_barrier();
            coff += H;
            float* tmp = cur; cur = alt; alt = tmp;
            H >>= 1;
        }
    }

    // FULL sync: drains every wave's crow stores before synthesis's global
    // readback of details0 (the one place vmcnt(0) is semantically required).
    __syncthreads();

    // ---------------- synthesis levels 7..1 (all-LDS) ----------------
    // out[n] = sum_{k≡n mod 2} d[((n+p)/2+m)&lm]*wav[k] + a[..]*sca[k], k=p+2m
    // wav sign (-1)^k with k=p+2m -> (p ? -1 : +1), folded per-u.
    const float* a = cs + 496;
    float* obuf = sa;   // 32->sa,64->sb,128->sa,256->sb,512->sa,1024->sb,2048->sa
    int len = 16;
    for (int lvl = NLVL - 1; lvl >= 1; --lvl) {
        float S[8], Wr[8];
#pragma unroll
        for (int k = 0; k < 8; ++k) {
            S[k]  = scaling[lvl * 8 + k];
            Wr[k] = scaling_rec[lvl * 8 + 7 - k];
        }
        const int Mout = len << 1;
        const int doff = LPAD - (LPAD >> lvl);
        const float4* d4 = (lvl >= 3) ? reinterpret_cast<const float4*>(cs + (doff - 3584))
                         : (lvl == 2) ? reinterpret_cast<const float4*>(sa + 512)
                                      : reinterpret_cast<const float4*>(sb + 1088);
        const float4* a4 = reinterpret_cast<const float4*>(a);
        const int gq = Mout >> 3;     // 8 outputs per work item
        const int fm = (len >> 2) - 1;
        for (int g = t; g < gq; g += 256) {
            F4 Da, Db, Aa, Ab;
            Da.v = d4[g]; Db.v = d4[(g + 1) & fm];
            Aa.v = a4[g]; Ab.v = a4[(g + 1) & fm];
            float dd[8] = {Da.f[0],Da.f[1],Da.f[2],Da.f[3],Db.f[0],Db.f[1],Db.f[2],Db.f[3]};
            float aa[8] = {Aa.f[0],Aa.f[1],Aa.f[2],Aa.f[3],Ab.f[0],Ab.f[1],Ab.f[2],Ab.f[3]};
            float out[8];
            __builtin_amdgcn_s_setprio(1);
#pragma unroll
            for (int u = 0; u < 8; ++u) {
                const int p = u & 1, c = (u + 1) >> 1;
                float s = 0.f;
#pragma unroll
                for (int m = 0; m < 4; ++m) {
                    const float w = Wr[p + 2 * m];
                    s = fmaf(dd[c + m], p ? -w : w, s);
                    s = fmaf(aa[c + m], S[p + 2 * m], s);
                }
                out[u] = s;
            }
            __builtin_amdgcn_s_setprio(0);
            F4 o0, o1;
            o0.f[0] = out[0]; o0.f[1] = out[1]; o0.f[2] = out[2]; o0.f[3] = out[3];
            o1.f[0] = out[4]; o1.f[1] = out[5]; o1.f[2] = out[6]; o1.f[3] = out[7];
            float4* ob4 = reinterpret_cast<float4*>(obuf + 8 * g);
            ob4[0] = o0.v; ob4[1] = o1.v;
        }
        lds_barrier();
        a = obuf;
        obuf = (obuf == sa) ? sb : sa;
        len = Mout;
    }
    // a == sa (2048 approx)

    // ---------------- synthesis level 0 : straight to recon ----------------
    {
        float S[8], Wr[8];
#pragma unroll
        for (int k = 0; k < 8; ++k) { S[k] = scaling[k]; Wr[k] = scaling_rec[7 - k]; }
        const float4* d4 = reinterpret_cast<const float4*>(crow);   // details0 (L2-warm)
        const float4* a4 = reinterpret_cast<const float4*>(a);
        const int fm = (len >> 2) - 1;                              // len == 2048
        float* const ro = recon_out + (size_t)row * MLEN;
        for (int g = t; g < (LPAD >> 3); g += 256) {
            F4 Da, Db, Aa, Ab;
            Da.v = d4[g]; Db.v = d4[(g + 1) & fm];
            Aa.v = a4[g]; Ab.v = a4[(g + 1) & fm];
            float dd[8] = {Da.f[0],Da.f[1],Da.f[2],Da.f[3],Db.f[0],Db.f[1],Db.f[2],Db.f[3]};
            float aa[8] = {Aa.f[0],Aa.f[1],Aa.f[2],Aa.f[3],Ab.f[0],Ab.f[1],Ab.f[2],Ab.f[3]};
            float out[8];
            __builtin_amdgcn_s_setprio(1);
#pragma unroll
            for (int u = 0; u < 8; ++u) {
                const int p = u & 1, c = (u + 1) >> 1;
                float s = 0.f;
#pragma unroll
                for (int m = 0; m < 4; ++m) {
                    const float w = Wr[p + 2 * m];
                    s = fmaf(dd[c + m], p ? -w : w, s);
                    s = fmaf(aa[c + m], S[p + 2 * m], s);
                }
                out[u] = s;
            }
            __builtin_amdgcn_s_setprio(0);
            const int n0 = 8 * g;
            if (n0 >= PAD0 && n0 + 8 <= PAD0 + MLEN) {
                F4 o0, o1;
                o0.f[0] = out[0]; o0.f[1] = out[1]; o0.f[2] = out[2]; o0.f[3] = out[3];
                o1.f[0] = out[4]; o1.f[1] = out[5]; o1.f[2] = out[6]; o1.f[3] = out[7];
                float4* r4 = reinterpret_cast<float4*>(ro + (n0 - PAD0));
                r4[0] = o0.v; r4[1] = o1.v;
            } else {
#pragma unroll
                for (int u = 0; u < 8; ++u) {
                    const int n = n0 + u;
                    if (n >= PAD0 && n < PAD0 + MLEN) ro[n - PAD0] = out[u];
                }
            }
        }
    }
}

extern "C" void kernel_launch(void* const* d_in, const int* in_sizes, int n_in,
                              void* d_out, int out_size, void* d_ws, size_t ws_size,
                              hipStream_t stream) {
    const float* x           = (const float*)d_in[0];
    const float* scaling     = (const float*)d_in[1];
    const float* scaling_rec = (const float*)d_in[2];
    float* recon = (float*)d_out;                       // 2048*3000 floats
    float* coefo = recon + (size_t)NROWS * MLEN;        // 2048*4096 floats
    despawn_kernel<<<dim3(NROWS / RPB), dim3(NT), 0, stream>>>(x, scaling, scaling_rec,
                                                               recon, coefo);
    (void)in_sizes; (void)n_in; (void)out_size; (void)d_ws; (void)ws_size;
}